// Round 6
// baseline (739.442 us; speedup 1.0000x reference)
//
#include <hip/hip_runtime.h>
#include <cfloat>
#include <cmath>

// ---------------------------------------------------------------------------
// Qwen3Attention fake-quant forward. B=2 S=1024 HID=2048 NH=16 NKV=8 D=128.
// Round 6: QK passes use 64-row blocks (grid 16x32=512, 2+ blocks/CU) and a
// u16 quant-level LDS tile (17 KB) in pv; projections stage LDS tiles via
// __builtin_amdgcn_global_load_lds width=16 (m97 ladder step).
// ---------------------------------------------------------------------------

#define FQ_EPS      1.5259021896696422e-09f   // 0.0001/65535
#define SCALING_F   0.08838834764831845f      // 128**-0.5
#define S_LEN       1024
#define PFLD        132                        // u16 LDS prob tile leading dim

typedef _Float16 h8_t __attribute__((ext_vector_type(8)));
typedef _Float16 h4_t __attribute__((ext_vector_type(4)));
typedef float    f4_t __attribute__((ext_vector_type(4)));
typedef unsigned short u16x4 __attribute__((ext_vector_type(4)));

// ---- float <-> order-preserving unsigned encoding (for atomic min/max) ----
__device__ __forceinline__ unsigned f2o(float f){
  unsigned u = __float_as_uint(f);
  return (u & 0x80000000u) ? ~u : (u | 0x80000000u);
}
__device__ __forceinline__ float o2f(unsigned u){
  return __uint_as_float((u & 0x80000000u) ? (u ^ 0x80000000u) : ~u);
}
__device__ __forceinline__ float dec_slot(const unsigned* st, int s){ return o2f(st[s*16]); }

// ---- fq16 helpers ----
struct FQP { float scale, zp, inv; };
__device__ __forceinline__ FQP fqp_raw(float mn, float mx){
  FQP p; p.scale = fmaxf((mx - mn)/65535.0f, FQ_EPS); p.zp = rintf(-mn/p.scale);
  p.inv = 1.0f/p.scale; return p;
}
__device__ __forceinline__ FQP fqp(float mn0, float mx0){
  return fqp_raw(fminf(mn0, 0.0f), fmaxf(mx0, 0.0f));
}
__device__ __forceinline__ float fqa(float x, FQP p){
  float q = rintf(x*p.inv) + p.zp;
  q = fminf(fmaxf(q, 0.0f), 65535.0f);
  return (q - p.zp)*p.scale;
}
__device__ __forceinline__ float fq8(float x, float s, float si){
  return fminf(fmaxf(rintf(x*si), -128.0f), 127.0f)*s;
}

// ---- block reductions (blockDim == 256) ----
__device__ __forceinline__ float bred_min(float v, float* red){
  int tid = threadIdx.x; red[tid] = v; __syncthreads();
  for (int s = 128; s > 0; s >>= 1){ if (tid < s) red[tid] = fminf(red[tid], red[tid+s]); __syncthreads(); }
  float r = red[0]; __syncthreads(); return r;
}
__device__ __forceinline__ float bred_max(float v, float* red){
  int tid = threadIdx.x; red[tid] = v; __syncthreads();
  for (int s = 128; s > 0; s >>= 1){ if (tid < s) red[tid] = fmaxf(red[tid], red[tid+s]); __syncthreads(); }
  float r = red[0]; __syncthreads(); return r;
}

// ---- stats slot map (even=min, odd=max) ----
// 0/1 hs | 2/3 qlin | 4/5 klin | 6/7 vlin | 8/9 qn | 10/11 qn2 | 12/13 kn | 14/15 kn2
// 16/17 q*c | 18/19 qrh*s | 20/21 k*c | 22/23 krh*s | 24/25 qsum | 26/27 ksum
// 28/29 logits | 31 unmaskedMax | 32 denomMin | 35 maxOfRowMins | 36/37 ctx

__global__ void k_init(unsigned* stats){
  int i = blockIdx.x*blockDim.x + threadIdx.x;
  if (i < 1024) stats[i] = (((i & 15) == 0) && (((i >> 4) & 1) == 0)) ? 0xFFFFFFFFu : 0u;
}

// lpbq weight quantization -> f16. 4 elems/thread; 8-lane shfl = 32-elem block.
__global__ __launch_bounds__(256) void k_quantw(const float* __restrict__ W, _Float16* __restrict__ Wh){
  int i = blockIdx.x*256 + threadIdx.x;
  float4 v = ((const float4*)W)[i];
  float am = fmaxf(fmaxf(fabsf(v.x), fabsf(v.y)), fmaxf(fabsf(v.z), fabsf(v.w)));
  #pragma unroll
  for (int m = 1; m < 8; m <<= 1) am = fmaxf(am, __shfl_xor(am, m, 64));
  float s = fmaxf(am/7.0f, 1e-12f), si = 1.0f/s;
  h4_t o;
  o[0] = (_Float16)(fminf(fmaxf(rintf(v.x*si), -8.0f), 7.0f)*s);
  o[1] = (_Float16)(fminf(fmaxf(rintf(v.y*si), -8.0f), 7.0f)*s);
  o[2] = (_Float16)(fminf(fmaxf(rintf(v.z*si), -8.0f), 7.0f)*s);
  o[3] = (_Float16)(fminf(fmaxf(rintf(v.w*si), -8.0f), 7.0f)*s);
  *(h4_t*)(Wh + ((size_t)i << 2)) = o;
}

__global__ __launch_bounds__(256) void k_minmax(const float* __restrict__ x, int n, unsigned* stats, int slot){
  float mn = FLT_MAX, mx = -FLT_MAX;
  for (int i = blockIdx.x*256 + threadIdx.x; i < n; i += gridDim.x*256){
    float v = x[i]; mn = fminf(mn, v); mx = fmaxf(mx, v);
  }
  __shared__ float red[256];
  float bmn = bred_min(mn, red), bmx = bred_max(mx, red);
  if (threadIdx.x == 0){ atomicMin(&stats[slot*16], f2o(bmn)); atomicMax(&stats[(slot+1)*16], f2o(bmx)); }
}

// fq16 elementwise -> f16, 4 elems/thread
__global__ __launch_bounds__(256) void k_fq_ew16(const float* __restrict__ x, _Float16* __restrict__ y,
                                                 const unsigned* stats, int slot){
  FQP p = fqp(dec_slot(stats, slot), dec_slot(stats, slot+1));
  int i = blockIdx.x*256 + threadIdx.x;
  float4 v = ((const float4*)x)[i];
  h4_t o;
  o[0] = (_Float16)fqa(v.x, p); o[1] = (_Float16)fqa(v.y, p);
  o[2] = (_Float16)fqa(v.z, p); o[3] = (_Float16)fqa(v.w, p);
  *(h4_t*)(y + ((size_t)i << 2)) = o;
}

// fq8(fq16(x)) elementwise -> f16 (for K)
__global__ __launch_bounds__(256) void k_fq8_ew16(const float* __restrict__ x, _Float16* __restrict__ y,
                                                  const unsigned* stats, int slot){
  FQP p = fqp(dec_slot(stats, slot), dec_slot(stats, slot+1));
  float lo = fqa(dec_slot(stats, slot), p), hi = fqa(dec_slot(stats, slot+1), p);
  float s8 = fmaxf(fmaxf(fabsf(lo), fabsf(hi))/127.0f, 1e-12f), s8i = 1.0f/s8;
  int i = blockIdx.x*256 + threadIdx.x;
  float4 v = ((const float4*)x)[i];
  h4_t o;
  o[0] = (_Float16)fq8(fqa(v.x, p), s8, s8i); o[1] = (_Float16)fq8(fqa(v.y, p), s8, s8i);
  o[2] = (_Float16)fq8(fqa(v.z, p), s8, s8i); o[3] = (_Float16)fq8(fqa(v.w, p), s8, s8i);
  *(h4_t*)(y + ((size_t)i << 2)) = o;
}

// ================= f16 MFMA GEMM core for projections (NT) =================
// async staging: LDS dest is wave-uniform base + lane*16B (constraint-safe).
#define GLDS16(g, l) __builtin_amdgcn_global_load_lds( \
    (__attribute__((address_space(1))) unsigned int*)(g), \
    (__attribute__((address_space(3))) unsigned int*)(l), 16, 0, 0)

__device__ __forceinline__ void stage_tile(const _Float16* __restrict__ src, int ld, int k0,
                                           _Float16* __restrict__ dst){
  #pragma unroll
  for (int it = 0; it < 2; it++){
    int c = threadIdx.x + (it << 8);
    int row = c >> 2, off = (c & 3) << 3;
    GLDS16(src + (size_t)row*ld + k0 + off, dst + (c << 3));
  }
}

__device__ __forceinline__ void hgemm_main(const _Float16* __restrict__ A, int lda,
                                           const _Float16* __restrict__ B, int ldb, int K,
                                           f4_t acc[4][4], _Float16* As, _Float16* Bs){
  int lane = threadIdx.x & 63, wave = threadIdx.x >> 6;
  int wm = wave & 1, wn = wave >> 1, quad = lane >> 4, l15 = lane & 15;
  for (int k0 = 0; k0 < K; k0 += 32){
    __syncthreads();
    stage_tile(A, lda, k0, As);
    stage_tile(B, ldb, k0, Bs);
    __syncthreads();
    h8_t af[4], bf[4];
    #pragma unroll
    for (int mt = 0; mt < 4; mt++)
      af[mt] = *(const h8_t*)(As + ((((wm<<6) + (mt<<4) + l15)) << 5) + (quad << 3));
    #pragma unroll
    for (int nt = 0; nt < 4; nt++)
      bf[nt] = *(const h8_t*)(Bs + ((((wn<<6) + (nt<<4) + l15)) << 5) + (quad << 3));
    #pragma unroll
    for (int mt = 0; mt < 4; mt++)
      #pragma unroll
      for (int nt = 0; nt < 4; nt++)
        acc[mt][nt] = __builtin_amdgcn_mfma_f32_16x16x32_f16(af[mt], bf[nt], acc[mt][nt], 0, 0, 0);
  }
}

#define HG_PROLOG  \
  __shared__ __align__(16) _Float16 As[4096], Bs[4096]; \
  __shared__ float red[256]; \
  f4_t acc[4][4]; \
  { f4_t zz = {0.f,0.f,0.f,0.f}; \
    for (int i=0;i<4;i++) for (int j=0;j<4;j++) acc[i][j] = zz; } \
  int lane = threadIdx.x & 63, wave = threadIdx.x >> 6; \
  int wm = wave & 1, wn = wave >> 1, quad = lane >> 4, l15 = lane & 15; (void)red; (void)lane;

// C/D lane map (m89-verified): D[row=(quad*4+reg)][col=l15].

__global__ __launch_bounds__(256) void k_hgemm_f(const _Float16* __restrict__ A, const _Float16* __restrict__ B,
                                                 float* __restrict__ C, int N, int K,
                                                 unsigned* stats, int slotC){
  HG_PROLOG
  int bm = blockIdx.y << 7, bn = blockIdx.x << 7;
  hgemm_main(A + (size_t)bm*K, K, B + (size_t)bn*K, K, K, acc, As, Bs);
  float mn = FLT_MAX, mx = -FLT_MAX;
  #pragma unroll
  for (int mt = 0; mt < 4; mt++)
    #pragma unroll
    for (int nt = 0; nt < 4; nt++){
      int Cc = bn + (wn<<6) + (nt<<4) + l15;
      #pragma unroll
      for (int i = 0; i < 4; i++){
        int R = bm + (wm<<6) + (mt<<4) + (quad<<2) + i;
        float v = acc[mt][nt][i];
        C[(size_t)R*N + Cc] = v;
        mn = fminf(mn, v); mx = fmaxf(mx, v);
      }
    }
  if (slotC >= 0){
    float bmn = bred_min(mn, red), bmx = bred_max(mx, red);
    if (threadIdx.x == 0){ atomicMin(&stats[slotC*16], f2o(bmn)); atomicMax(&stats[(slotC+1)*16], f2o(bmx)); }
  }
}

// fused K/V projections: z=0 -> (Bk, Ck, slot4), z=1 -> (Bv, Cv, slot6)
__global__ __launch_bounds__(256) void k_hgemm_kv(const _Float16* __restrict__ A,
                                                  const _Float16* __restrict__ Bk, const _Float16* __restrict__ Bv,
                                                  float* __restrict__ Ck, float* __restrict__ Cv,
                                                  int K, unsigned* stats){
  HG_PROLOG
  const _Float16* B = blockIdx.z ? Bv : Bk;
  float* C = blockIdx.z ? Cv : Ck;
  int slotC = blockIdx.z ? 6 : 4;
  int bm = blockIdx.y << 7, bn = blockIdx.x << 7;
  hgemm_main(A + (size_t)bm*K, K, B + (size_t)bn*K, K, K, acc, As, Bs);
  float mn = FLT_MAX, mx = -FLT_MAX;
  #pragma unroll
  for (int mt = 0; mt < 4; mt++)
    #pragma unroll
    for (int nt = 0; nt < 4; nt++){
      int Cc = bn + (wn<<6) + (nt<<4) + l15;
      #pragma unroll
      for (int i = 0; i < 4; i++){
        int R = bm + (wm<<6) + (mt<<4) + (quad<<2) + i;
        float v = acc[mt][nt][i];
        C[(size_t)R*1024 + Cc] = v;
        mn = fminf(mn, v); mx = fmaxf(mx, v);
      }
    }
  float bmn = bred_min(mn, red), bmx = bred_max(mx, red);
  if (threadIdx.x == 0){ atomicMin(&stats[slotC*16], f2o(bmn)); atomicMax(&stats[(slotC+1)*16], f2o(bmx)); }
}

// ====================== full-row QK^T attention passes =====================
// block = 256 thr (2x2 waves), owns 64 q-rows x ALL 1024 t (8 chunks of 128).
// Per wave: 32 rows (wm) x 64 cols (wn), acc[2][4]. Deterministic across
// passes: per chunk acc zeroed, same k0/mfma order, shared qk_chunk64.

#define QK_IDS \
  int lane = threadIdx.x & 63, wave = threadIdx.x >> 6; \
  int wm = wave & 1, wn = wave >> 1, quad = lane >> 4, l15 = lane & 15; \
  int tid = threadIdx.x; (void)tid; (void)lane;

__device__ __forceinline__ void qk_chunk64(const _Float16* __restrict__ Ab, const _Float16* __restrict__ Kb,
                                           int bn, int wn, int quad, int l15, f4_t acc[2][4]){
  const _Float16* Bb = Kb + (size_t)(bn + (wn<<6))*128;
  #pragma unroll
  for (int k0 = 0; k0 < 4; k0++){
    h8_t af[2], bf[4];
    #pragma unroll
    for (int mt = 0; mt < 2; mt++)
      af[mt] = *(const h8_t*)(Ab + (size_t)((mt<<4) + l15)*128 + (k0<<5) + (quad<<3));
    #pragma unroll
    for (int nt = 0; nt < 4; nt++)
      bf[nt] = *(const h8_t*)(Bb + (size_t)((nt<<4) + l15)*128 + (k0<<5) + (quad<<3));
    #pragma unroll
    for (int mt = 0; mt < 2; mt++)
      #pragma unroll
      for (int nt = 0; nt < 4; nt++)
        acc[mt][nt] = __builtin_amdgcn_mfma_f32_16x16x32_f16(af[mt], bf[nt], acc[mt][nt], 0, 0, 0);
  }
}

// pass 1: global logit stats + per-row min / unmasked max (direct stores)
__global__ __launch_bounds__(256) void k_qk_stats(const _Float16* __restrict__ q_h, const _Float16* __restrict__ k_h,
                                                  unsigned* stats, unsigned* rowmin, unsigned* rowmax){
  QK_IDS
  int bm = blockIdx.x << 6, z = blockIdx.y;
  int b = z >> 4, h = z & 15;
  const _Float16* Ab = q_h + (size_t)z*131072 + (size_t)(bm + (wm<<5))*128;
  const _Float16* Kb = k_h + (size_t)(b*8 + (h>>1))*131072;
  float rmv[2][4], rxv[2][4];
  #pragma unroll
  for (int mt = 0; mt < 2; mt++)
    #pragma unroll
    for (int i = 0; i < 4; i++){ rmv[mt][i] = FLT_MAX; rxv[mt][i] = -FLT_MAX; }
  float mn = FLT_MAX, mx = -FLT_MAX, mxU = -FLT_MAX;
  for (int bn = 0; bn < 1024; bn += 128){
    f4_t acc[2][4];
    { f4_t zz = {0.f,0.f,0.f,0.f}; for (int i=0;i<2;i++) for (int j=0;j<4;j++) acc[i][j]=zz; }
    qk_chunk64(Ab, Kb, bn, wn, quad, l15, acc);
    #pragma unroll
    for (int mt = 0; mt < 2; mt++){
      int rb = bm + (wm<<5) + (mt<<4) + (quad<<2);
      #pragma unroll
      for (int nt = 0; nt < 4; nt++){
        int t = bn + (wn<<6) + (nt<<4) + l15;
        #pragma unroll
        for (int i = 0; i < 4; i++){
          float v = acc[mt][nt][i];
          mn = fminf(mn, v); mx = fmaxf(mx, v);
          rmv[mt][i] = fminf(rmv[mt][i], v);
          if (t <= rb + i){ mxU = fmaxf(mxU, v); rxv[mt][i] = fmaxf(rxv[mt][i], v); }
        }
      }
    }
  }
  #pragma unroll
  for (int d = 1; d < 16; d <<= 1)
    #pragma unroll
    for (int mt = 0; mt < 2; mt++)
      #pragma unroll
      for (int i = 0; i < 4; i++){
        rmv[mt][i] = fminf(rmv[mt][i], __shfl_xor(rmv[mt][i], d, 64));
        rxv[mt][i] = fmaxf(rxv[mt][i], __shfl_xor(rxv[mt][i], d, 64));
      }
  __shared__ float rminS[2][64], rmaxS[2][64];
  if (l15 == 0){
    #pragma unroll
    for (int mt = 0; mt < 2; mt++)
      #pragma unroll
      for (int i = 0; i < 4; i++){
        int rl = (wm<<5) + (mt<<4) + (quad<<2) + i;
        rminS[wn][rl] = rmv[mt][i];
        rmaxS[wn][rl] = rxv[mt][i];
      }
  }
  __syncthreads();
  if (tid < 64){
    rowmin[(z << 10) + bm + tid] = f2o(fminf(rminS[0][tid], rminS[1][tid]));
    rowmax[(z << 10) + bm + tid] = f2o(fmaxf(rmaxS[0][tid], rmaxS[1][tid]));
  }
  __shared__ float red[256];
  float bmn = bred_min(mn, red), bmx = bred_max(mx, red), bmU = bred_max(mxU, red);
  if (tid == 0){
    atomicMin(&stats[28*16], f2o(bmn));
    atomicMax(&stats[29*16], f2o(bmx));
    atomicMax(&stats[31*16], f2o(bmU));
  }
}

__global__ __launch_bounds__(256) void k_rowstat_m2(const unsigned* __restrict__ rowmin, unsigned* stats, int n){
  float lm = -FLT_MAX;
  for (int i = blockIdx.x*256 + threadIdx.x; i < n; i += gridDim.x*256) lm = fmaxf(lm, o2f(rowmin[i]));
  __shared__ float red[256];
  float m = bred_max(lm, red);
  if (threadIdx.x == 0) atomicMax(&stats[35*16], f2o(m));
}
__global__ __launch_bounds__(256) void k_denom_min(const float* __restrict__ denomS, unsigned* stats, int n){
  float lm = FLT_MAX;
  for (int i = blockIdx.x*256 + threadIdx.x; i < n; i += gridDim.x*256) lm = fminf(lm, denomS[i]);
  __shared__ float red[256];
  float m = -bred_max(-lm, red);
  if (threadIdx.x == 0) atomicMin(&stats[32*16], f2o(m));
}

struct LogitQ { FQP f1, f2, fam, fvv, f3; float sc, c20; };
__device__ LogitQ derive_logit(const unsigned* st){
  LogitQ L;
  FQP ps = fqp(SCALING_F, SCALING_F); L.sc = fqa(SCALING_F, ps);
  FQP p20 = fqp(-20.0f, -20.0f);      L.c20 = fqa(-20.0f, p20);
  float gmn = dec_slot(st, 28), gmx = dec_slot(st, 29);
  float gU = dec_slot(st, 31), M2 = dec_slot(st, 35);
  L.f1 = fqp(gmn, gmx);
  float l1lo = fqa(gmn, L.f1), l1hi = fqa(gmx, L.f1);
  L.f2 = fqp(l1lo*L.sc, l1hi*L.sc);
  float amlo = fqa(fqa(gmn, L.f1)*L.sc, L.f2);
  float amhi = fqa(fqa(M2, L.f1)*L.sc, L.f2);
  L.fam = fqp(amlo, amhi);
  float vslo = fqa(amlo, L.fam) + L.c20, vshi = fqa(amhi, L.fam) + L.c20;
  L.fvv = fqp(vslo, vshi);
  float mn3 = fqa(vslo, L.fvv);
  float mx3 = fqa(fqa(gU, L.f1)*L.sc, L.f2);
  L.f3 = fqp(mn3, mx3);
  return L;
}
__device__ __forceinline__ float chainU(float raw, const LogitQ& L){
  return fqa(fqa(fqa(raw, L.f1)*L.sc, L.f2), L.f3);
}
__device__ __forceinline__ float row_vv3(const unsigned* rowmin, int row, const LogitQ& L){
  float tr = fqa(fqa(o2f(rowmin[row]), L.f1)*L.sc, L.f2);
  return fqa(fqa(fqa(tr, L.fam) + L.c20, L.fvv), L.f3);
}

// pass 2: recompute QK, per-row denominators accumulated in-block, direct store
__global__ __launch_bounds__(256) void k_qk_denom(const _Float16* __restrict__ q_h, const _Float16* __restrict__ k_h,
                                                  const unsigned* __restrict__ rowmin,
                                                  const unsigned* __restrict__ rowmax,
                                                  float* __restrict__ denomS, const unsigned* stats){
  QK_IDS
  int bm = blockIdx.x << 6, z = blockIdx.y;
  int b = z >> 4, h = z & 15;
  LogitQ L = derive_logit(stats);
  __shared__ float mRow[64], vvRow[64];
  if (tid < 64){
    int r = (z << 10) + bm + tid;
    mRow[tid] = chainU(o2f(rowmax[r]), L);
    vvRow[tid] = row_vv3(rowmin, r, L);
  }
  __syncthreads();
  const _Float16* Ab = q_h + (size_t)z*131072 + (size_t)(bm + (wm<<5))*128;
  const _Float16* Kb = k_h + (size_t)(b*8 + (h>>1))*131072;
  float rs[2][4];
  #pragma unroll
  for (int mt = 0; mt < 2; mt++)
    #pragma unroll
    for (int i = 0; i < 4; i++) rs[mt][i] = 0.0f;
  for (int bn = 0; bn < 1024; bn += 128){
    f4_t acc[2][4];
    { f4_t zz = {0.f,0.f,0.f,0.f}; for (int i=0;i<2;i++) for (int j=0;j<4;j++) acc[i][j]=zz; }
    qk_chunk64(Ab, Kb, bn, wn, quad, l15, acc);
    #pragma unroll
    for (int mt = 0; mt < 2; mt++){
      int rl = (wm<<5) + (mt<<4) + (quad<<2);
      #pragma unroll
      for (int nt = 0; nt < 4; nt++){
        int t = bn + (wn<<6) + (nt<<4) + l15;
        #pragma unroll
        for (int i = 0; i < 4; i++){
          float a2 = fqa(fqa(acc[mt][nt][i], L.f1)*L.sc, L.f2);
          float a3 = (t <= bm + rl + i) ? fqa(a2, L.f3) : vvRow[rl + i];
          rs[mt][i] += __expf(a3 - mRow[rl + i]);
        }
      }
    }
  }
  #pragma unroll
  for (int d = 1; d < 16; d <<= 1)
    #pragma unroll
    for (int mt = 0; mt < 2; mt++)
      #pragma unroll
      for (int i = 0; i < 4; i++) rs[mt][i] += __shfl_xor(rs[mt][i], d, 64);
  __shared__ float dS[2][64];
  if (l15 == 0){
    #pragma unroll
    for (int mt = 0; mt < 2; mt++)
      #pragma unroll
      for (int i = 0; i < 4; i++){
        int rl = (wm<<5) + (mt<<4) + (quad<<2) + i;
        dS[wn][rl] = rs[mt][i];
      }
  }
  __syncthreads();
  if (tid < 64) denomS[(z << 10) + bm + tid] = dS[0][tid] + dS[1][tid];
}

// pass 3: recompute QK, probs as u16 quant levels in LDS (17 KB), stream attn
// out contiguously, PV accumulated in registers, direct ctx store + stats.
__global__ __launch_bounds__(256) void k_qk_pv(const _Float16* __restrict__ q_h, const _Float16* __restrict__ k_h,
                                               const _Float16* __restrict__ vT,
                                               float* __restrict__ attn, float* __restrict__ ctx,
                                               const unsigned* __restrict__ rowmin,
                                               const unsigned* __restrict__ rowmax,
                                               const float* __restrict__ denomS, unsigned* stats){
  QK_IDS
  __shared__ __align__(16) unsigned short Pu[64*PFLD];
  __shared__ float mRow[64], vvRow[64], rdRow[64];
  int bm = blockIdx.x << 6, z = blockIdx.y;
  int b = z >> 4, h = z & 15;
  LogitQ L = derive_logit(stats);
  FQP p4 = fqp(0.0f, 1.0f/dec_slot(stats, 32));
  if (tid < 64){
    int r = (z << 10) + bm + tid;
    mRow[tid] = chainU(o2f(rowmax[r]), L);
    vvRow[tid] = row_vv3(rowmin, r, L);
    rdRow[tid] = 1.0f/denomS[r];
  }
  const _Float16* Ab = q_h + (size_t)z*131072 + (size_t)(bm + (wm<<5))*128;
  const _Float16* Kb = k_h + (size_t)(b*8 + (h>>1))*131072;
  const _Float16* Vb = vT + (size_t)(b*8 + (h>>1))*131072;
  float* Cp = attn + ((size_t)z << 20) + (size_t)bm*1024;
  f4_t pacc[2][4];
  { f4_t zz = {0.f,0.f,0.f,0.f}; for (int i=0;i<2;i++) for (int j=0;j<4;j++) pacc[i][j]=zz; }
  for (int bn = 0; bn < 1024; bn += 128){
    f4_t acc[2][4];
    { f4_t zz = {0.f,0.f,0.f,0.f}; for (int i=0;i<2;i++) for (int j=0;j<4;j++) acc[i][j]=zz; }
    qk_chunk64(Ab, Kb, bn, wn, quad, l15, acc);
    __syncthreads();   // prev chunk's Pu consumed; also orders param LDS on iter 0
    #pragma unroll
    for (int mt = 0; mt < 2; mt++){
      int rl = (wm<<5) + (mt<<4) + (quad<<2);
      #pragma unroll
      for (int nt = 0; nt < 4; nt++){
        int cl = (wn<<6) + (nt<<4) + l15;
        int t = bn + cl;
        #pragma unroll
        for (int i = 0; i < 4; i++){
          float a2 = fqa(fqa(acc[mt][nt][i], L.f1)*L.sc, L.f2);
          float a3 = (t <= bm + rl + i) ? fqa(a2, L.f3) : vvRow[rl + i];
          float p = __expf(a3 - mRow[rl + i])*rdRow[rl + i];
          float n = fminf(fmaxf(rintf(p*p4.inv), 0.0f), 65535.0f);   // fqa's q (zp=0)
          Pu[(rl + i)*PFLD + cl] = (unsigned short)n;
        }
      }
    }
    __syncthreads();
    // stream attn: pq = n*scale (bitwise == fqa result); contiguous float4
    #pragma unroll
    for (int it = 0; it < 8; it++){
      int flat = (it << 10) + (tid << 2);
      int row = flat >> 7, col = flat & 127;
      const unsigned short* pp = &Pu[row*PFLD + col];
      u16x4 nv = *(const u16x4*)pp;
      f4_t v4;
      v4[0] = (float)nv[0]*p4.scale; v4[1] = (float)nv[1]*p4.scale;
      v4[2] = (float)nv[2]*p4.scale; v4[3] = (float)nv[3]*p4.scale;
      __builtin_nontemporal_store(v4, (f4_t*)(Cp + (size_t)row*1024 + bn + col));
    }
    // PV: pacc[r][d] += P[r][t-chunk] * vT[d][t-chunk]
    #pragma unroll
    for (int k0 = 0; k0 < 4; k0++){
      h8_t af[2], bf[4];
      #pragma unroll
      for (int mt = 0; mt < 2; mt++){
        const unsigned short* pr = &Pu[((wm<<5) + (mt<<4) + l15)*PFLD + (k0<<5) + (quad<<3)];
        u16x4 u = *(const u16x4*)pr, w = *(const u16x4*)(pr + 4);
        h8_t o;
        o[0]=(_Float16)(((float)u[0]*p4.scale)*1024.f); o[1]=(_Float16)(((float)u[1]*p4.scale)*1024.f);
        o[2]=(_Float16)(((float)u[2]*p4.scale)*1024.f); o[3]=(_Float16)(((float)u[3]*p4.scale)*1024.f);
        o[4]=(_Float16)(((float)w[0]*p4.scale)*1024.f); o[5]=(_Float16)(((float)w[1]*p4.scale)*1024.f);
        o[6]=(_Float16)(((float)w[2]*p4.scale)*1024.f); o[7]=(_Float16)(((float)w[3]*p4.scale)*1024.f);
        af[mt] = o;
      }
      #pragma unroll
      for (int nt = 0; nt < 4; nt++)
        bf[nt] = *(const h8_t*)(Vb + (size_t)((wn<<6) + (nt<<4) + l15)*1024 + bn + (k0<<5) + (quad<<3));
      #pragma unroll
      for (int mt = 0; mt < 2; mt++)
        #pragma unroll
        for (int nt = 0; nt < 4; nt++)
          pacc[mt][nt] = __builtin_amdgcn_mfma_f32_16x16x32_f16(af[mt], bf[nt], pacc[mt][nt], 0, 0, 0);
    }
  }
  // direct ctx store (block exclusively owns rows bm..bm+63 of head h) + stats
  float* Cb = ctx + ((size_t)b << 10)*2048 + (size_t)h*128;
  float mn = FLT_MAX, mx = -FLT_MAX;
  #pragma unroll
  for (int mt = 0; mt < 2; mt++)
    #pragma unroll
    for (int nt = 0; nt < 4; nt++){
      int Cc = (wn<<6) + (nt<<4) + l15;
      #pragma unroll
      for (int i = 0; i < 4; i++){
        int R = bm + (wm<<5) + (mt<<4) + (quad<<2) + i;
        float v = pacc[mt][nt][i]*(1.0f/1024.0f);
        Cb[(size_t)R*2048 + Cc] = v;
        mn = fminf(mn, v); mx = fmaxf(mx, v);
      }
    }
  __shared__ float red[256];
  float bmn = bred_min(mn, red), bmx = bred_max(mx, red);
  if (tid == 0){ atomicMin(&stats[36*16], f2o(bmn)); atomicMax(&stats[37*16], f2o(bmx)); }
}

// ===========================================================================

// fq16(A) then per-128 rmsnorm; writes (B,NH,S,D) fp32; reduces full+half ranges
__global__ __launch_bounds__(256) void k_rms(const float* __restrict__ lin, float* __restrict__ buf,
                                             const float* __restrict__ gw, unsigned* stats,
                                             int slot_lin, int slot_out, int NHh, int rows){
  FQP pA = fqp(dec_slot(stats, slot_lin), dec_slot(stats, slot_lin+1));
  int lane = threadIdx.x & 63;
  int wv = (blockIdx.x*256 + threadIdx.x) >> 6;
  int nwv = (gridDim.x*256) >> 6;
  float w0 = gw[lane], w1 = gw[lane + 64];
  float fmn = FLT_MAX, fmx = -FLT_MAX, hmn = FLT_MAX, hmx = -FLT_MAX;
  for (int r = wv; r < rows; r += nwv){
    int h = r % NHh; int rem = r / NHh; int s2 = rem & 1023; int b = rem >> 10;
    const float* src = lin + (size_t)r*128;
    float x0 = fqa(src[lane], pA), x1 = fqa(src[lane + 64], pA);
    float ss = x0*x0 + x1*x1;
    #pragma unroll
    for (int m = 1; m < 64; m <<= 1) ss += __shfl_xor(ss, m, 64);
    float rr = 1.0f/sqrtf(ss*(1.0f/128.0f) + 1e-6f);
    float y0 = x0*rr*w0, y1 = x1*rr*w1;
    float* dst = buf + ((size_t)((b*NHh + h) << 10) + s2)*128;
    dst[lane] = y0; dst[lane + 64] = y1;
    fmn = fminf(fmn, fminf(y0, y1)); fmx = fmaxf(fmx, fmaxf(y0, y1));
    hmn = fminf(hmn, y1); hmx = fmaxf(hmx, y1);
  }
  __shared__ float red[256];
  float a = bred_min(fmn, red), bb = bred_max(fmx, red);
  float c = bred_min(hmn, red), d = bred_max(hmx, red);
  if (threadIdx.x == 0){
    atomicMin(&stats[slot_out*16], f2o(a));     atomicMax(&stats[(slot_out+1)*16], f2o(bb));
    atomicMin(&stats[(slot_out+2)*16], f2o(c)); atomicMax(&stats[(slot_out+3)*16], f2o(d));
  }
}

struct RopeQ { FQP B, C, E, F; };
__device__ RopeQ derive_rope(const unsigned* st, int base){
  float ymn = dec_slot(st, base),   ymx = dec_slot(st, base+1);
  float y2mn = dec_slot(st, base+2), y2mx = dec_slot(st, base+3);
  RopeQ r;
  r.B = fqp(ymn, ymx);
  float zmn = fqa(ymn, r.B), zmx = fqa(ymx, r.B);
  r.C = fqp(zmn, zmx);
  float zlo = fqa(zmn, r.C), zhi = fqa(zmx, r.C);
  float z2lo = fqa(fqa(y2mn, r.B), r.C), z2hi = fqa(fqa(y2mx, r.B), r.C);
  r.E = fqp(-z2hi, -z2lo);
  float nlo = fqa(-z2hi, r.E), nhi = fqa(-z2lo, r.E);
  r.F = fqp_raw(fminf(fminf(zlo, nlo), 0.0f), fmaxf(fmaxf(zhi, nhi), 0.0f));
  return r;
}

__global__ __launch_bounds__(256) void k_rope(float* __restrict__ buf, const float* __restrict__ cosp,
                                              const float* __restrict__ sinp, unsigned* stats,
                                              int slot_norm, int slot_prod, int slot_sum,
                                              int NHh, int rows, int do_write){
  RopeQ R = derive_rope(stats, slot_norm);
  FQP pD, pG;
  if (do_write){
    pD = fqp(dec_slot(stats, slot_prod),   dec_slot(stats, slot_prod+1));
    pG = fqp(dec_slot(stats, slot_prod+2), dec_slot(stats, slot_prod+3));
  }
  int lane = threadIdx.x & 63;
  int wv = (blockIdx.x*256 + threadIdx.x) >> 6, nwv = (gridDim.x*256) >> 6;
  float m0 = FLT_MAX, M0 = -FLT_MAX, m1 = FLT_MAX, M1 = -FLT_MAX;
  for (int r = wv; r < rows; r += nwv){
    int s2 = r & 1023; int bh = r >> 10; int b = bh/NHh;
    float* base = buf + (size_t)r*128;
    float y0 = base[lane], y1 = base[lane + 64];
    float z0 = fqa(fqa(y0, R.B), R.C), z1 = fqa(fqa(y1, R.B), R.C);
    const float* cr = cosp + (size_t)((b << 10) + s2)*128;
    const float* sr = sinp + (size_t)((b << 10) + s2)*128;
    float c0 = cr[lane], c1 = cr[lane + 64], sn0 = sr[lane], sn1 = sr[lane + 64];
    float pc0 = z0*c0, pc1 = z1*c1;
    float rh0 = fqa(fqa(-z1, R.E), R.F);
    float rh1 = fqa(z0, R.F);
    float ps0 = rh0*sn0, ps1 = rh1*sn1;
    if (!do_write){
      m0 = fminf(m0, fminf(pc0, pc1)); M0 = fmaxf(M0, fmaxf(pc0, pc1));
      m1 = fminf(m1, fminf(ps0, ps1)); M1 = fmaxf(M1, fmaxf(ps0, ps1));
    } else {
      float sv0 = fqa(pc0, pD) + fqa(ps0, pG);
      float sv1 = fqa(pc1, pD) + fqa(ps1, pG);
      base[lane] = sv0; base[lane + 64] = sv1;
      m0 = fminf(m0, fminf(sv0, sv1)); M0 = fmaxf(M0, fmaxf(sv0, sv1));
    }
  }
  __shared__ float red[256];
  if (!do_write){
    float a = bred_min(m0, red), bb = bred_max(M0, red);
    float c = bred_min(m1, red), d = bred_max(M1, red);
    if (threadIdx.x == 0){
      atomicMin(&stats[slot_prod*16], f2o(a));     atomicMax(&stats[(slot_prod+1)*16], f2o(bb));
      atomicMin(&stats[(slot_prod+2)*16], f2o(c)); atomicMax(&stats[(slot_prod+3)*16], f2o(d));
    }
  } else {
    float a = bred_min(m0, red), bb = bred_max(M0, red);
    if (threadIdx.x == 0){ atomicMin(&stats[slot_sum*16], f2o(a)); atomicMax(&stats[(slot_sum+1)*16], f2o(bb)); }
  }
}

// V transpose + fq8(fq16) -> f16: vT[b][kv][d][t]
__global__ __launch_bounds__(256) void k_vT(const float* __restrict__ vlin, _Float16* __restrict__ vT,
                                            const unsigned* stats){
  FQP pv = fqp(dec_slot(stats, 6), dec_slot(stats, 7));
  float vlo = fqa(dec_slot(stats, 6), pv), vhi = fqa(dec_slot(stats, 7), pv);
  float v8s = fmaxf(fmaxf(fabsf(vlo), fabsf(vhi))/127.0f, 1e-12f), v8si = 1.0f/v8s;
  __shared__ float tile[64][65];
  int bkv = blockIdx.z, t0 = blockIdx.x << 6, d0 = blockIdx.y << 6;
  int b = bkv >> 3, kv = bkv & 7;
  const float* src = vlin + ((size_t)(b << 10))*1024 + (size_t)kv*128;
  int tx = threadIdx.x & 63, tq = threadIdx.x >> 6;
  #pragma unroll
  for (int i = 0; i < 16; i++){
    int tt = (i << 2) + tq;
    float x = src[(size_t)(t0 + tt)*1024 + d0 + tx];
    tile[tx][tt] = fq8(fqa(x, pv), v8s, v8si);
  }
  __syncthreads();
  _Float16* dst = vT + (size_t)bkv*131072;
  #pragma unroll
  for (int i = 0; i < 16; i++){
    int dd = (i << 2) + tq;
    dst[(size_t)(d0 + dd)*1024 + t0 + tx] = (_Float16)tile[dd][tx];
  }
}

extern "C" void kernel_launch(void* const* d_in, const int* in_sizes, int n_in,
                              void* d_out, int out_size, void* d_ws, size_t ws_size,
                              hipStream_t stream){
  (void)in_sizes; (void)n_in; (void)out_size; (void)ws_size;
  const float* hs   = (const float*)d_in[0];
  const float* cosp = (const float*)d_in[1];
  const float* sinp = (const float*)d_in[2];
  const float* Wq   = (const float*)d_in[4];
  const float* Wk   = (const float*)d_in[5];
  const float* Wv   = (const float*)d_in[6];
  const float* Wo   = (const float*)d_in[7];
  const float* qnw  = (const float*)d_in[8];
  const float* knw  = (const float*)d_in[9];

  float* outp = (float*)d_out;
  float* attn = outp + 4194304;      // final quantized softmax, written once by k_qk_pv

  const size_t MEG = 1u << 20;       // floats
  float* wsf = (float*)d_ws;
  _Float16* woq_h = (_Float16*)(wsf + 0);
  _Float16* wqq_h = (_Float16*)(wsf + 2*MEG);
  _Float16* wkq_h = (_Float16*)(wsf + 4*MEG);
  _Float16* wvq_h = (_Float16*)(wsf + 5*MEG);
  _Float16* hsq_h = (_Float16*)(wsf + 6*MEG);
  float* qlin = wsf + 8*MEG;  float* ctx = qlin;   // ctx reuses qlin (every elem stored by PV)
  float* klin = wsf + 12*MEG;
  float* vlin = wsf + 14*MEG;
  float* qbuf = wsf + 16*MEG;
  float* kbuf = wsf + 20*MEG;
  _Float16* q_h   = (_Float16*)(wsf + 22*MEG);
  _Float16* k_h   = (_Float16*)(wsf + 24*MEG);
  _Float16* vT_h  = (_Float16*)(wsf + 25*MEG);
  _Float16* ctx_h = (_Float16*)(wsf + 26*MEG);
  unsigned* rowmin = (unsigned*)(wsf + 28*MEG);
  unsigned* rowmax = (unsigned*)(wsf + 28*MEG + 32768);
  float* denomS = wsf + 28*MEG + 65536;
  unsigned* stats = (unsigned*)(wsf + 28*MEG + 98304);

  k_init<<<4, 256, 0, stream>>>(stats);

  k_quantw<<<4096, 256, 0, stream>>>(Wq, wqq_h);
  k_quantw<<<2048, 256, 0, stream>>>(Wk, wkq_h);
  k_quantw<<<2048, 256, 0, stream>>>(Wv, wvq_h);
  k_quantw<<<4096, 256, 0, stream>>>(Wo, woq_h);

  k_minmax<<<1024, 256, 0, stream>>>(hs, 4194304, stats, 0);
  k_fq_ew16<<<4096, 256, 0, stream>>>(hs, hsq_h, stats, 0);

  // projections (f16 MFMA, async LDS staging), raw-output range stats fused
  k_hgemm_f<<<dim3(16, 16), 256, 0, stream>>>(hsq_h, wqq_h, qlin, 2048, 2048, stats, 2);
  k_hgemm_kv<<<dim3(8, 16, 2), 256, 0, stream>>>(hsq_h, wkq_h, wvq_h, klin, vlin, 2048, stats);

  // fq16 + rmsnorm (fp32) + range reductions
  k_rms<<<1024, 256, 0, stream>>>(qlin, qbuf, qnw, stats, 2, 8, 16, 32768);
  k_rms<<<512, 256, 0, stream>>>(klin, kbuf, knw, stats, 4, 12, 8, 16384);

  // RoPE: range pass then write pass
  k_rope<<<1024, 256, 0, stream>>>(qbuf, cosp, sinp, stats, 8, 16, 24, 16, 32768, 0);
  k_rope<<<512, 256, 0, stream>>>(kbuf, cosp, sinp, stats, 12, 20, 26, 8, 16384, 0);
  k_rope<<<1024, 256, 0, stream>>>(qbuf, cosp, sinp, stats, 8, 16, 24, 16, 32768, 1);
  k_rope<<<512, 256, 0, stream>>>(kbuf, cosp, sinp, stats, 12, 20, 26, 8, 16384, 1);

  // operand conversion for QK and V transpose
  k_fq_ew16<<<4096, 256, 0, stream>>>(qbuf, q_h, stats, 24);
  k_fq8_ew16<<<2048, 256, 0, stream>>>(kbuf, k_h, stats, 26);
  k_vT<<<dim3(16, 2, 16), 256, 0, stream>>>(vlin, vT_h, stats);

  // 64-row-block attention passes (no logit materialization, no accum atomics)
  k_qk_stats<<<dim3(16, 32), 256, 0, stream>>>(q_h, k_h, stats, rowmin, rowmax);
  k_rowstat_m2<<<8, 256, 0, stream>>>(rowmin, stats, 32768);
  k_qk_denom<<<dim3(16, 32), 256, 0, stream>>>(q_h, k_h, rowmin, rowmax, denomS, stats);
  k_denom_min<<<8, 256, 0, stream>>>(denomS, stats, 32768);
  k_qk_pv<<<dim3(16, 32), 256, 0, stream>>>(q_h, k_h, vT_h, attn, ctx, rowmin, rowmax, denomS, stats);

  // ctx (stats fused in PV) -> f16 -> O-proj
  k_fq_ew16<<<4096, 256, 0, stream>>>(ctx, ctx_h, stats, 36);
  k_hgemm_f<<<dim3(16, 16), 256, 0, stream>>>(ctx_h, woq_h, outp, 2048, 2048, stats, -1);
}

// Round 7
// 709.129 us; speedup vs baseline: 1.0427x; 1.0427x over previous
//
#include <hip/hip_runtime.h>
#include <cfloat>
#include <cmath>

// ---------------------------------------------------------------------------
// Qwen3Attention fake-quant forward. B=2 S=1024 HID=2048 NH=16 NKV=8 D=128.
// Round 7: QK sweeps use 32-row blocks (grid 32x32=1024, ~3-4 blocks/CU) with
// A-fragments hoisted into registers (loaded once, reused across all 8
// k-chunks). Each wave: 32 rows x 32-col slice, acc[2][2]. u16 prob tile.
// ---------------------------------------------------------------------------

#define FQ_EPS      1.5259021896696422e-09f   // 0.0001/65535
#define SCALING_F   0.08838834764831845f      // 128**-0.5
#define S_LEN       1024
#define PFLD        132                        // u16 LDS prob tile leading dim

typedef _Float16 h8_t __attribute__((ext_vector_type(8)));
typedef _Float16 h4_t __attribute__((ext_vector_type(4)));
typedef float    f4_t __attribute__((ext_vector_type(4)));
typedef unsigned short u16x4 __attribute__((ext_vector_type(4)));

// ---- float <-> order-preserving unsigned encoding (for atomic min/max) ----
__device__ __forceinline__ unsigned f2o(float f){
  unsigned u = __float_as_uint(f);
  return (u & 0x80000000u) ? ~u : (u | 0x80000000u);
}
__device__ __forceinline__ float o2f(unsigned u){
  return __uint_as_float((u & 0x80000000u) ? (u ^ 0x80000000u) : ~u);
}
__device__ __forceinline__ float dec_slot(const unsigned* st, int s){ return o2f(st[s*16]); }

// ---- fq16 helpers ----
struct FQP { float scale, zp, inv; };
__device__ __forceinline__ FQP fqp_raw(float mn, float mx){
  FQP p; p.scale = fmaxf((mx - mn)/65535.0f, FQ_EPS); p.zp = rintf(-mn/p.scale);
  p.inv = 1.0f/p.scale; return p;
}
__device__ __forceinline__ FQP fqp(float mn0, float mx0){
  return fqp_raw(fminf(mn0, 0.0f), fmaxf(mx0, 0.0f));
}
__device__ __forceinline__ float fqa(float x, FQP p){
  float q = rintf(x*p.inv) + p.zp;
  q = fminf(fmaxf(q, 0.0f), 65535.0f);
  return (q - p.zp)*p.scale;
}
__device__ __forceinline__ float fq8(float x, float s, float si){
  return fminf(fmaxf(rintf(x*si), -128.0f), 127.0f)*s;
}

// ---- block reductions (blockDim == 256) ----
__device__ __forceinline__ float bred_min(float v, float* red){
  int tid = threadIdx.x; red[tid] = v; __syncthreads();
  for (int s = 128; s > 0; s >>= 1){ if (tid < s) red[tid] = fminf(red[tid], red[tid+s]); __syncthreads(); }
  float r = red[0]; __syncthreads(); return r;
}
__device__ __forceinline__ float bred_max(float v, float* red){
  int tid = threadIdx.x; red[tid] = v; __syncthreads();
  for (int s = 128; s > 0; s >>= 1){ if (tid < s) red[tid] = fmaxf(red[tid], red[tid+s]); __syncthreads(); }
  float r = red[0]; __syncthreads(); return r;
}

// ---- stats slot map (even=min, odd=max) ----
// 0/1 hs | 2/3 qlin | 4/5 klin | 6/7 vlin | 8/9 qn | 10/11 qn2 | 12/13 kn | 14/15 kn2
// 16/17 q*c | 18/19 qrh*s | 20/21 k*c | 22/23 krh*s | 24/25 qsum | 26/27 ksum
// 28/29 logits | 31 unmaskedMax | 32 denomMin | 35 maxOfRowMins | 36/37 ctx

__global__ void k_init(unsigned* stats){
  int i = blockIdx.x*blockDim.x + threadIdx.x;
  if (i < 1024) stats[i] = (((i & 15) == 0) && (((i >> 4) & 1) == 0)) ? 0xFFFFFFFFu : 0u;
}

// lpbq weight quantization -> f16. 4 elems/thread; 8-lane shfl = 32-elem block.
__global__ __launch_bounds__(256) void k_quantw(const float* __restrict__ W, _Float16* __restrict__ Wh){
  int i = blockIdx.x*256 + threadIdx.x;
  float4 v = ((const float4*)W)[i];
  float am = fmaxf(fmaxf(fabsf(v.x), fabsf(v.y)), fmaxf(fabsf(v.z), fabsf(v.w)));
  #pragma unroll
  for (int m = 1; m < 8; m <<= 1) am = fmaxf(am, __shfl_xor(am, m, 64));
  float s = fmaxf(am/7.0f, 1e-12f), si = 1.0f/s;
  h4_t o;
  o[0] = (_Float16)(fminf(fmaxf(rintf(v.x*si), -8.0f), 7.0f)*s);
  o[1] = (_Float16)(fminf(fmaxf(rintf(v.y*si), -8.0f), 7.0f)*s);
  o[2] = (_Float16)(fminf(fmaxf(rintf(v.z*si), -8.0f), 7.0f)*s);
  o[3] = (_Float16)(fminf(fmaxf(rintf(v.w*si), -8.0f), 7.0f)*s);
  *(h4_t*)(Wh + ((size_t)i << 2)) = o;
}

__global__ __launch_bounds__(256) void k_minmax(const float* __restrict__ x, int n, unsigned* stats, int slot){
  float mn = FLT_MAX, mx = -FLT_MAX;
  for (int i = blockIdx.x*256 + threadIdx.x; i < n; i += gridDim.x*256){
    float v = x[i]; mn = fminf(mn, v); mx = fmaxf(mx, v);
  }
  __shared__ float red[256];
  float bmn = bred_min(mn, red), bmx = bred_max(mx, red);
  if (threadIdx.x == 0){ atomicMin(&stats[slot*16], f2o(bmn)); atomicMax(&stats[(slot+1)*16], f2o(bmx)); }
}

// fq16 elementwise -> f16, 4 elems/thread
__global__ __launch_bounds__(256) void k_fq_ew16(const float* __restrict__ x, _Float16* __restrict__ y,
                                                 const unsigned* stats, int slot){
  FQP p = fqp(dec_slot(stats, slot), dec_slot(stats, slot+1));
  int i = blockIdx.x*256 + threadIdx.x;
  float4 v = ((const float4*)x)[i];
  h4_t o;
  o[0] = (_Float16)fqa(v.x, p); o[1] = (_Float16)fqa(v.y, p);
  o[2] = (_Float16)fqa(v.z, p); o[3] = (_Float16)fqa(v.w, p);
  *(h4_t*)(y + ((size_t)i << 2)) = o;
}

// fq8(fq16(x)) elementwise -> f16 (for K)
__global__ __launch_bounds__(256) void k_fq8_ew16(const float* __restrict__ x, _Float16* __restrict__ y,
                                                  const unsigned* stats, int slot){
  FQP p = fqp(dec_slot(stats, slot), dec_slot(stats, slot+1));
  float lo = fqa(dec_slot(stats, slot), p), hi = fqa(dec_slot(stats, slot+1), p);
  float s8 = fmaxf(fmaxf(fabsf(lo), fabsf(hi))/127.0f, 1e-12f), s8i = 1.0f/s8;
  int i = blockIdx.x*256 + threadIdx.x;
  float4 v = ((const float4*)x)[i];
  h4_t o;
  o[0] = (_Float16)fq8(fqa(v.x, p), s8, s8i); o[1] = (_Float16)fq8(fqa(v.y, p), s8, s8i);
  o[2] = (_Float16)fq8(fqa(v.z, p), s8, s8i); o[3] = (_Float16)fq8(fqa(v.w, p), s8, s8i);
  *(h4_t*)(y + ((size_t)i << 2)) = o;
}

// ================= f16 MFMA GEMM core for projections (NT) =================
// async staging: LDS dest is wave-uniform base + lane*16B (constraint-safe).
#define GLDS16(g, l) __builtin_amdgcn_global_load_lds( \
    (__attribute__((address_space(1))) unsigned int*)(g), \
    (__attribute__((address_space(3))) unsigned int*)(l), 16, 0, 0)

__device__ __forceinline__ void stage_tile(const _Float16* __restrict__ src, int ld, int k0,
                                           _Float16* __restrict__ dst){
  #pragma unroll
  for (int it = 0; it < 2; it++){
    int c = threadIdx.x + (it << 8);
    int row = c >> 2, off = (c & 3) << 3;
    GLDS16(src + (size_t)row*ld + k0 + off, dst + (c << 3));
  }
}

__device__ __forceinline__ void hgemm_main(const _Float16* __restrict__ A, int lda,
                                           const _Float16* __restrict__ B, int ldb, int K,
                                           f4_t acc[4][4], _Float16* As, _Float16* Bs){
  int lane = threadIdx.x & 63, wave = threadIdx.x >> 6;
  int wm = wave & 1, wn = wave >> 1, quad = lane >> 4, l15 = lane & 15;
  for (int k0 = 0; k0 < K; k0 += 32){
    __syncthreads();
    stage_tile(A, lda, k0, As);
    stage_tile(B, ldb, k0, Bs);
    __syncthreads();
    h8_t af[4], bf[4];
    #pragma unroll
    for (int mt = 0; mt < 4; mt++)
      af[mt] = *(const h8_t*)(As + ((((wm<<6) + (mt<<4) + l15)) << 5) + (quad << 3));
    #pragma unroll
    for (int nt = 0; nt < 4; nt++)
      bf[nt] = *(const h8_t*)(Bs + ((((wn<<6) + (nt<<4) + l15)) << 5) + (quad << 3));
    #pragma unroll
    for (int mt = 0; mt < 4; mt++)
      #pragma unroll
      for (int nt = 0; nt < 4; nt++)
        acc[mt][nt] = __builtin_amdgcn_mfma_f32_16x16x32_f16(af[mt], bf[nt], acc[mt][nt], 0, 0, 0);
  }
}

#define HG_PROLOG  \
  __shared__ __align__(16) _Float16 As[4096], Bs[4096]; \
  __shared__ float red[256]; \
  f4_t acc[4][4]; \
  { f4_t zz = {0.f,0.f,0.f,0.f}; \
    for (int i=0;i<4;i++) for (int j=0;j<4;j++) acc[i][j] = zz; } \
  int lane = threadIdx.x & 63, wave = threadIdx.x >> 6; \
  int wm = wave & 1, wn = wave >> 1, quad = lane >> 4, l15 = lane & 15; (void)red; (void)lane;

// C/D lane map (m89-verified): D[row=(quad*4+reg)][col=l15].

__global__ __launch_bounds__(256) void k_hgemm_f(const _Float16* __restrict__ A, const _Float16* __restrict__ B,
                                                 float* __restrict__ C, int N, int K,
                                                 unsigned* stats, int slotC){
  HG_PROLOG
  int bm = blockIdx.y << 7, bn = blockIdx.x << 7;
  hgemm_main(A + (size_t)bm*K, K, B + (size_t)bn*K, K, K, acc, As, Bs);
  float mn = FLT_MAX, mx = -FLT_MAX;
  #pragma unroll
  for (int mt = 0; mt < 4; mt++)
    #pragma unroll
    for (int nt = 0; nt < 4; nt++){
      int Cc = bn + (wn<<6) + (nt<<4) + l15;
      #pragma unroll
      for (int i = 0; i < 4; i++){
        int R = bm + (wm<<6) + (mt<<4) + (quad<<2) + i;
        float v = acc[mt][nt][i];
        C[(size_t)R*N + Cc] = v;
        mn = fminf(mn, v); mx = fmaxf(mx, v);
      }
    }
  if (slotC >= 0){
    float bmn = bred_min(mn, red), bmx = bred_max(mx, red);
    if (threadIdx.x == 0){ atomicMin(&stats[slotC*16], f2o(bmn)); atomicMax(&stats[(slotC+1)*16], f2o(bmx)); }
  }
}

// fused K/V projections: z=0 -> (Bk, Ck, slot4), z=1 -> (Bv, Cv, slot6)
__global__ __launch_bounds__(256) void k_hgemm_kv(const _Float16* __restrict__ A,
                                                  const _Float16* __restrict__ Bk, const _Float16* __restrict__ Bv,
                                                  float* __restrict__ Ck, float* __restrict__ Cv,
                                                  int K, unsigned* stats){
  HG_PROLOG
  const _Float16* B = blockIdx.z ? Bv : Bk;
  float* C = blockIdx.z ? Cv : Ck;
  int slotC = blockIdx.z ? 6 : 4;
  int bm = blockIdx.y << 7, bn = blockIdx.x << 7;
  hgemm_main(A + (size_t)bm*K, K, B + (size_t)bn*K, K, K, acc, As, Bs);
  float mn = FLT_MAX, mx = -FLT_MAX;
  #pragma unroll
  for (int mt = 0; mt < 4; mt++)
    #pragma unroll
    for (int nt = 0; nt < 4; nt++){
      int Cc = bn + (wn<<6) + (nt<<4) + l15;
      #pragma unroll
      for (int i = 0; i < 4; i++){
        int R = bm + (wm<<6) + (mt<<4) + (quad<<2) + i;
        float v = acc[mt][nt][i];
        C[(size_t)R*1024 + Cc] = v;
        mn = fminf(mn, v); mx = fmaxf(mx, v);
      }
    }
  float bmn = bred_min(mn, red), bmx = bred_max(mx, red);
  if (threadIdx.x == 0){ atomicMin(&stats[slotC*16], f2o(bmn)); atomicMax(&stats[(slotC+1)*16], f2o(bmx)); }
}

// ====================== QK^T attention passes (32-row) =====================
// block = 256 thr (4 waves). Block owns 32 q-rows x ALL 1024 t (8 chunks).
// Wave wn owns all 32 rows x cols [32*wn, 32*wn+32) of each chunk: acc[2][2].
// A-frags (q rows x 128 dims) hoisted into registers once per block.
// Deterministic across passes: identical qk_load_a/qk_chunk32 chain.

#define QK_IDS \
  int lane = threadIdx.x & 63, wn = threadIdx.x >> 6; \
  int quad = lane >> 4, l15 = lane & 15; \
  int tid = threadIdx.x; (void)tid; (void)lane;

__device__ __forceinline__ void qk_load_a(const _Float16* __restrict__ Ab, int quad, int l15,
                                          h8_t Aq[2][4]){
  #pragma unroll
  for (int mt = 0; mt < 2; mt++)
    #pragma unroll
    for (int k0 = 0; k0 < 4; k0++)
      Aq[mt][k0] = *(const h8_t*)(Ab + (size_t)((mt<<4) + l15)*128 + (k0<<5) + (quad<<3));
}

__device__ __forceinline__ void qk_chunk32(const h8_t Aq[2][4], const _Float16* __restrict__ Kb,
                                           int bn, int wn, int quad, int l15, f4_t acc[2][2]){
  #pragma unroll
  for (int k0 = 0; k0 < 4; k0++){
    h8_t bf[2];
    #pragma unroll
    for (int nt = 0; nt < 2; nt++)
      bf[nt] = *(const h8_t*)(Kb + (size_t)(bn + (wn<<5) + (nt<<4) + l15)*128 + (k0<<5) + (quad<<3));
    #pragma unroll
    for (int mt = 0; mt < 2; mt++)
      #pragma unroll
      for (int nt = 0; nt < 2; nt++)
        acc[mt][nt] = __builtin_amdgcn_mfma_f32_16x16x32_f16(Aq[mt][k0], bf[nt], acc[mt][nt], 0, 0, 0);
  }
}

// pass 1: global logit stats + per-row min / unmasked max (direct stores)
__global__ __launch_bounds__(256) void k_qk_stats(const _Float16* __restrict__ q_h, const _Float16* __restrict__ k_h,
                                                  unsigned* stats, unsigned* rowmin, unsigned* rowmax){
  QK_IDS
  int bm = blockIdx.x << 5, z = blockIdx.y;
  int b = z >> 4, h = z & 15;
  const _Float16* Ab = q_h + (size_t)z*131072 + (size_t)bm*128;
  const _Float16* Kb = k_h + (size_t)(b*8 + (h>>1))*131072;
  h8_t Aq[2][4];
  qk_load_a(Ab, quad, l15, Aq);
  float rmv[2][4], rxv[2][4];
  #pragma unroll
  for (int mt = 0; mt < 2; mt++)
    #pragma unroll
    for (int i = 0; i < 4; i++){ rmv[mt][i] = FLT_MAX; rxv[mt][i] = -FLT_MAX; }
  float mn = FLT_MAX, mx = -FLT_MAX, mxU = -FLT_MAX;
  for (int bn = 0; bn < 1024; bn += 128){
    f4_t acc[2][2];
    { f4_t zz = {0.f,0.f,0.f,0.f}; for (int i=0;i<2;i++) for (int j=0;j<2;j++) acc[i][j]=zz; }
    qk_chunk32(Aq, Kb, bn, wn, quad, l15, acc);
    #pragma unroll
    for (int mt = 0; mt < 2; mt++){
      int rb = bm + (mt<<4) + (quad<<2);
      #pragma unroll
      for (int nt = 0; nt < 2; nt++){
        int t = bn + (wn<<5) + (nt<<4) + l15;
        #pragma unroll
        for (int i = 0; i < 4; i++){
          float v = acc[mt][nt][i];
          mn = fminf(mn, v); mx = fmaxf(mx, v);
          rmv[mt][i] = fminf(rmv[mt][i], v);
          if (t <= rb + i){ mxU = fmaxf(mxU, v); rxv[mt][i] = fmaxf(rxv[mt][i], v); }
        }
      }
    }
  }
  #pragma unroll
  for (int d = 1; d < 16; d <<= 1)
    #pragma unroll
    for (int mt = 0; mt < 2; mt++)
      #pragma unroll
      for (int i = 0; i < 4; i++){
        rmv[mt][i] = fminf(rmv[mt][i], __shfl_xor(rmv[mt][i], d, 64));
        rxv[mt][i] = fmaxf(rxv[mt][i], __shfl_xor(rxv[mt][i], d, 64));
      }
  __shared__ float rminS[4][32], rmaxS[4][32];
  if (l15 == 0){
    #pragma unroll
    for (int mt = 0; mt < 2; mt++)
      #pragma unroll
      for (int i = 0; i < 4; i++){
        int rl = (mt<<4) + (quad<<2) + i;
        rminS[wn][rl] = rmv[mt][i];
        rmaxS[wn][rl] = rxv[mt][i];
      }
  }
  __syncthreads();
  if (tid < 32){
    float a = fminf(fminf(rminS[0][tid], rminS[1][tid]), fminf(rminS[2][tid], rminS[3][tid]));
    float c = fmaxf(fmaxf(rmaxS[0][tid], rmaxS[1][tid]), fmaxf(rmaxS[2][tid], rmaxS[3][tid]));
    rowmin[(z << 10) + bm + tid] = f2o(a);
    rowmax[(z << 10) + bm + tid] = f2o(c);
  }
  __shared__ float red[256];
  float bmn = bred_min(mn, red), bmx = bred_max(mx, red), bmU = bred_max(mxU, red);
  if (tid == 0){
    atomicMin(&stats[28*16], f2o(bmn));
    atomicMax(&stats[29*16], f2o(bmx));
    atomicMax(&stats[31*16], f2o(bmU));
  }
}

__global__ __launch_bounds__(256) void k_rowstat_m2(const unsigned* __restrict__ rowmin, unsigned* stats, int n){
  float lm = -FLT_MAX;
  for (int i = blockIdx.x*256 + threadIdx.x; i < n; i += gridDim.x*256) lm = fmaxf(lm, o2f(rowmin[i]));
  __shared__ float red[256];
  float m = bred_max(lm, red);
  if (threadIdx.x == 0) atomicMax(&stats[35*16], f2o(m));
}
__global__ __launch_bounds__(256) void k_denom_min(const float* __restrict__ denomS, unsigned* stats, int n){
  float lm = FLT_MAX;
  for (int i = blockIdx.x*256 + threadIdx.x; i < n; i += gridDim.x*256) lm = fminf(lm, denomS[i]);
  __shared__ float red[256];
  float m = -bred_max(-lm, red);
  if (threadIdx.x == 0) atomicMin(&stats[32*16], f2o(m));
}

struct LogitQ { FQP f1, f2, fam, fvv, f3; float sc, c20; };
__device__ LogitQ derive_logit(const unsigned* st){
  LogitQ L;
  FQP ps = fqp(SCALING_F, SCALING_F); L.sc = fqa(SCALING_F, ps);
  FQP p20 = fqp(-20.0f, -20.0f);      L.c20 = fqa(-20.0f, p20);
  float gmn = dec_slot(st, 28), gmx = dec_slot(st, 29);
  float gU = dec_slot(st, 31), M2 = dec_slot(st, 35);
  L.f1 = fqp(gmn, gmx);
  float l1lo = fqa(gmn, L.f1), l1hi = fqa(gmx, L.f1);
  L.f2 = fqp(l1lo*L.sc, l1hi*L.sc);
  float amlo = fqa(fqa(gmn, L.f1)*L.sc, L.f2);
  float amhi = fqa(fqa(M2, L.f1)*L.sc, L.f2);
  L.fam = fqp(amlo, amhi);
  float vslo = fqa(amlo, L.fam) + L.c20, vshi = fqa(amhi, L.fam) + L.c20;
  L.fvv = fqp(vslo, vshi);
  float mn3 = fqa(vslo, L.fvv);
  float mx3 = fqa(fqa(gU, L.f1)*L.sc, L.f2);
  L.f3 = fqp(mn3, mx3);
  return L;
}
__device__ __forceinline__ float chainU(float raw, const LogitQ& L){
  return fqa(fqa(fqa(raw, L.f1)*L.sc, L.f2), L.f3);
}
__device__ __forceinline__ float row_vv3(const unsigned* rowmin, int row, const LogitQ& L){
  float tr = fqa(fqa(o2f(rowmin[row]), L.f1)*L.sc, L.f2);
  return fqa(fqa(fqa(tr, L.fam) + L.c20, L.fvv), L.f3);
}

// pass 2: recompute QK, per-row denominators accumulated in-block, direct store
__global__ __launch_bounds__(256) void k_qk_denom(const _Float16* __restrict__ q_h, const _Float16* __restrict__ k_h,
                                                  const unsigned* __restrict__ rowmin,
                                                  const unsigned* __restrict__ rowmax,
                                                  float* __restrict__ denomS, const unsigned* stats){
  QK_IDS
  int bm = blockIdx.x << 5, z = blockIdx.y;
  int b = z >> 4, h = z & 15;
  LogitQ L = derive_logit(stats);
  __shared__ float mRow[32], vvRow[32];
  if (tid < 32){
    int r = (z << 10) + bm + tid;
    mRow[tid] = chainU(o2f(rowmax[r]), L);
    vvRow[tid] = row_vv3(rowmin, r, L);
  }
  const _Float16* Ab = q_h + (size_t)z*131072 + (size_t)bm*128;
  const _Float16* Kb = k_h + (size_t)(b*8 + (h>>1))*131072;
  h8_t Aq[2][4];
  qk_load_a(Ab, quad, l15, Aq);
  __syncthreads();
  float rs[2][4];
  #pragma unroll
  for (int mt = 0; mt < 2; mt++)
    #pragma unroll
    for (int i = 0; i < 4; i++) rs[mt][i] = 0.0f;
  for (int bn = 0; bn < 1024; bn += 128){
    f4_t acc[2][2];
    { f4_t zz = {0.f,0.f,0.f,0.f}; for (int i=0;i<2;i++) for (int j=0;j<2;j++) acc[i][j]=zz; }
    qk_chunk32(Aq, Kb, bn, wn, quad, l15, acc);
    #pragma unroll
    for (int mt = 0; mt < 2; mt++){
      int rl = (mt<<4) + (quad<<2);
      #pragma unroll
      for (int nt = 0; nt < 2; nt++){
        int t = bn + (wn<<5) + (nt<<4) + l15;
        #pragma unroll
        for (int i = 0; i < 4; i++){
          float a2 = fqa(fqa(acc[mt][nt][i], L.f1)*L.sc, L.f2);
          float a3 = (t <= bm + rl + i) ? fqa(a2, L.f3) : vvRow[rl + i];
          rs[mt][i] += __expf(a3 - mRow[rl + i]);
        }
      }
    }
  }
  #pragma unroll
  for (int d = 1; d < 16; d <<= 1)
    #pragma unroll
    for (int mt = 0; mt < 2; mt++)
      #pragma unroll
      for (int i = 0; i < 4; i++) rs[mt][i] += __shfl_xor(rs[mt][i], d, 64);
  __shared__ float dS[4][32];
  if (l15 == 0){
    #pragma unroll
    for (int mt = 0; mt < 2; mt++)
      #pragma unroll
      for (int i = 0; i < 4; i++){
        int rl = (mt<<4) + (quad<<2) + i;
        dS[wn][rl] = rs[mt][i];
      }
  }
  __syncthreads();
  if (tid < 32) denomS[(z << 10) + bm + tid] = (dS[0][tid] + dS[1][tid]) + (dS[2][tid] + dS[3][tid]);
}

// pass 3: recompute QK, probs as u16 quant levels in LDS (8.4 KB), stream attn
// out contiguously, PV accumulated in registers, direct ctx store + stats.
__global__ __launch_bounds__(256) void k_qk_pv(const _Float16* __restrict__ q_h, const _Float16* __restrict__ k_h,
                                               const _Float16* __restrict__ vT,
                                               float* __restrict__ attn, float* __restrict__ ctx,
                                               const unsigned* __restrict__ rowmin,
                                               const unsigned* __restrict__ rowmax,
                                               const float* __restrict__ denomS, unsigned* stats){
  QK_IDS
  __shared__ __align__(16) unsigned short Pu[32*PFLD];
  __shared__ float mRow[32], vvRow[32], rdRow[32];
  int bm = blockIdx.x << 5, z = blockIdx.y;
  int b = z >> 4, h = z & 15;
  LogitQ L = derive_logit(stats);
  FQP p4 = fqp(0.0f, 1.0f/dec_slot(stats, 32));
  if (tid < 32){
    int r = (z << 10) + bm + tid;
    mRow[tid] = chainU(o2f(rowmax[r]), L);
    vvRow[tid] = row_vv3(rowmin, r, L);
    rdRow[tid] = 1.0f/denomS[r];
  }
  const _Float16* Ab = q_h + (size_t)z*131072 + (size_t)bm*128;
  const _Float16* Kb = k_h + (size_t)(b*8 + (h>>1))*131072;
  const _Float16* Vb = vT + (size_t)(b*8 + (h>>1))*131072;
  float* Cp = attn + ((size_t)z << 20) + (size_t)bm*1024;
  h8_t Aq[2][4];
  qk_load_a(Ab, quad, l15, Aq);
  f4_t pacc[2][2];
  { f4_t zz = {0.f,0.f,0.f,0.f}; for (int i=0;i<2;i++) for (int j=0;j<2;j++) pacc[i][j]=zz; }
  for (int bn = 0; bn < 1024; bn += 128){
    f4_t acc[2][2];
    { f4_t zz = {0.f,0.f,0.f,0.f}; for (int i=0;i<2;i++) for (int j=0;j<2;j++) acc[i][j]=zz; }
    qk_chunk32(Aq, Kb, bn, wn, quad, l15, acc);
    __syncthreads();   // prev chunk's Pu consumed; also orders param LDS on iter 0
    #pragma unroll
    for (int mt = 0; mt < 2; mt++){
      int rl = (mt<<4) + (quad<<2);
      #pragma unroll
      for (int nt = 0; nt < 2; nt++){
        int cl = (wn<<5) + (nt<<4) + l15;
        int t = bn + cl;
        #pragma unroll
        for (int i = 0; i < 4; i++){
          float a2 = fqa(fqa(acc[mt][nt][i], L.f1)*L.sc, L.f2);
          float a3 = (t <= bm + rl + i) ? fqa(a2, L.f3) : vvRow[rl + i];
          float p = __expf(a3 - mRow[rl + i])*rdRow[rl + i];
          float n = fminf(fmaxf(rintf(p*p4.inv), 0.0f), 65535.0f);   // fqa's q (zp=0)
          Pu[(rl + i)*PFLD + cl] = (unsigned short)n;
        }
      }
    }
    __syncthreads();
    // stream attn: pq = n*scale (bitwise == fqa result); contiguous float4
    #pragma unroll
    for (int it = 0; it < 4; it++){
      int flat = (it << 10) + (tid << 2);
      int row = flat >> 7, col = flat & 127;
      const unsigned short* pp = &Pu[row*PFLD + col];
      u16x4 nv = *(const u16x4*)pp;
      f4_t v4;
      v4[0] = (float)nv[0]*p4.scale; v4[1] = (float)nv[1]*p4.scale;
      v4[2] = (float)nv[2]*p4.scale; v4[3] = (float)nv[3]*p4.scale;
      __builtin_nontemporal_store(v4, (f4_t*)(Cp + (size_t)row*1024 + bn + col));
    }
    // PV: pacc[r][d] += P[r][t-chunk] * vT[d][t-chunk]
    #pragma unroll
    for (int k0 = 0; k0 < 4; k0++){
      h8_t af[2], bf[2];
      #pragma unroll
      for (int mt = 0; mt < 2; mt++){
        const unsigned short* pr = &Pu[((mt<<4) + l15)*PFLD + (k0<<5) + (quad<<3)];
        u16x4 u = *(const u16x4*)pr, w = *(const u16x4*)(pr + 4);
        h8_t o;
        o[0]=(_Float16)(((float)u[0]*p4.scale)*1024.f); o[1]=(_Float16)(((float)u[1]*p4.scale)*1024.f);
        o[2]=(_Float16)(((float)u[2]*p4.scale)*1024.f); o[3]=(_Float16)(((float)u[3]*p4.scale)*1024.f);
        o[4]=(_Float16)(((float)w[0]*p4.scale)*1024.f); o[5]=(_Float16)(((float)w[1]*p4.scale)*1024.f);
        o[6]=(_Float16)(((float)w[2]*p4.scale)*1024.f); o[7]=(_Float16)(((float)w[3]*p4.scale)*1024.f);
        af[mt] = o;
      }
      #pragma unroll
      for (int nt = 0; nt < 2; nt++)
        bf[nt] = *(const h8_t*)(Vb + (size_t)((wn<<5) + (nt<<4) + l15)*1024 + bn + (k0<<5) + (quad<<3));
      #pragma unroll
      for (int mt = 0; mt < 2; mt++)
        #pragma unroll
        for (int nt = 0; nt < 2; nt++)
          pacc[mt][nt] = __builtin_amdgcn_mfma_f32_16x16x32_f16(af[mt], bf[nt], pacc[mt][nt], 0, 0, 0);
    }
  }
  // direct ctx store (block exclusively owns rows bm..bm+31 of head h) + stats
  float* Cb = ctx + ((size_t)b << 10)*2048 + (size_t)h*128;
  float mn = FLT_MAX, mx = -FLT_MAX;
  #pragma unroll
  for (int mt = 0; mt < 2; mt++)
    #pragma unroll
    for (int nt = 0; nt < 2; nt++){
      int Cc = (wn<<5) + (nt<<4) + l15;
      #pragma unroll
      for (int i = 0; i < 4; i++){
        int R = bm + (mt<<4) + (quad<<2) + i;
        float v = pacc[mt][nt][i]*(1.0f/1024.0f);
        Cb[(size_t)R*2048 + Cc] = v;
        mn = fminf(mn, v); mx = fmaxf(mx, v);
      }
    }
  __shared__ float red[256];
  float bmn = bred_min(mn, red), bmx = bred_max(mx, red);
  if (tid == 0){ atomicMin(&stats[36*16], f2o(bmn)); atomicMax(&stats[37*16], f2o(bmx)); }
}

// ===========================================================================

// fq16(A) then per-128 rmsnorm; writes (B,NH,S,D) fp32; reduces full+half ranges
__global__ __launch_bounds__(256) void k_rms(const float* __restrict__ lin, float* __restrict__ buf,
                                             const float* __restrict__ gw, unsigned* stats,
                                             int slot_lin, int slot_out, int NHh, int rows){
  FQP pA = fqp(dec_slot(stats, slot_lin), dec_slot(stats, slot_lin+1));
  int lane = threadIdx.x & 63;
  int wv = (blockIdx.x*256 + threadIdx.x) >> 6;
  int nwv = (gridDim.x*256) >> 6;
  float w0 = gw[lane], w1 = gw[lane + 64];
  float fmn = FLT_MAX, fmx = -FLT_MAX, hmn = FLT_MAX, hmx = -FLT_MAX;
  for (int r = wv; r < rows; r += nwv){
    int h = r % NHh; int rem = r / NHh; int s2 = rem & 1023; int b = rem >> 10;
    const float* src = lin + (size_t)r*128;
    float x0 = fqa(src[lane], pA), x1 = fqa(src[lane + 64], pA);
    float ss = x0*x0 + x1*x1;
    #pragma unroll
    for (int m = 1; m < 64; m <<= 1) ss += __shfl_xor(ss, m, 64);
    float rr = 1.0f/sqrtf(ss*(1.0f/128.0f) + 1e-6f);
    float y0 = x0*rr*w0, y1 = x1*rr*w1;
    float* dst = buf + ((size_t)((b*NHh + h) << 10) + s2)*128;
    dst[lane] = y0; dst[lane + 64] = y1;
    fmn = fminf(fmn, fminf(y0, y1)); fmx = fmaxf(fmx, fmaxf(y0, y1));
    hmn = fminf(hmn, y1); hmx = fmaxf(hmx, y1);
  }
  __shared__ float red[256];
  float a = bred_min(fmn, red), bb = bred_max(fmx, red);
  float c = bred_min(hmn, red), d = bred_max(hmx, red);
  if (threadIdx.x == 0){
    atomicMin(&stats[slot_out*16], f2o(a));     atomicMax(&stats[(slot_out+1)*16], f2o(bb));
    atomicMin(&stats[(slot_out+2)*16], f2o(c)); atomicMax(&stats[(slot_out+3)*16], f2o(d));
  }
}

struct RopeQ { FQP B, C, E, F; };
__device__ RopeQ derive_rope(const unsigned* st, int base){
  float ymn = dec_slot(st, base),   ymx = dec_slot(st, base+1);
  float y2mn = dec_slot(st, base+2), y2mx = dec_slot(st, base+3);
  RopeQ r;
  r.B = fqp(ymn, ymx);
  float zmn = fqa(ymn, r.B), zmx = fqa(ymx, r.B);
  r.C = fqp(zmn, zmx);
  float zlo = fqa(zmn, r.C), zhi = fqa(zmx, r.C);
  float z2lo = fqa(fqa(y2mn, r.B), r.C), z2hi = fqa(fqa(y2mx, r.B), r.C);
  r.E = fqp(-z2hi, -z2lo);
  float nlo = fqa(-z2hi, r.E), nhi = fqa(-z2lo, r.E);
  r.F = fqp_raw(fminf(fminf(zlo, nlo), 0.0f), fmaxf(fmaxf(zhi, nhi), 0.0f));
  return r;
}

__global__ __launch_bounds__(256) void k_rope(float* __restrict__ buf, const float* __restrict__ cosp,
                                              const float* __restrict__ sinp, unsigned* stats,
                                              int slot_norm, int slot_prod, int slot_sum,
                                              int NHh, int rows, int do_write){
  RopeQ R = derive_rope(stats, slot_norm);
  FQP pD, pG;
  if (do_write){
    pD = fqp(dec_slot(stats, slot_prod),   dec_slot(stats, slot_prod+1));
    pG = fqp(dec_slot(stats, slot_prod+2), dec_slot(stats, slot_prod+3));
  }
  int lane = threadIdx.x & 63;
  int wv = (blockIdx.x*256 + threadIdx.x) >> 6, nwv = (gridDim.x*256) >> 6;
  float m0 = FLT_MAX, M0 = -FLT_MAX, m1 = FLT_MAX, M1 = -FLT_MAX;
  for (int r = wv; r < rows; r += nwv){
    int s2 = r & 1023; int bh = r >> 10; int b = bh/NHh;
    float* base = buf + (size_t)r*128;
    float y0 = base[lane], y1 = base[lane + 64];
    float z0 = fqa(fqa(y0, R.B), R.C), z1 = fqa(fqa(y1, R.B), R.C);
    const float* cr = cosp + (size_t)((b << 10) + s2)*128;
    const float* sr = sinp + (size_t)((b << 10) + s2)*128;
    float c0 = cr[lane], c1 = cr[lane + 64], sn0 = sr[lane], sn1 = sr[lane + 64];
    float pc0 = z0*c0, pc1 = z1*c1;
    float rh0 = fqa(fqa(-z1, R.E), R.F);
    float rh1 = fqa(z0, R.F);
    float ps0 = rh0*sn0, ps1 = rh1*sn1;
    if (!do_write){
      m0 = fminf(m0, fminf(pc0, pc1)); M0 = fmaxf(M0, fmaxf(pc0, pc1));
      m1 = fminf(m1, fminf(ps0, ps1)); M1 = fmaxf(M1, fmaxf(ps0, ps1));
    } else {
      float sv0 = fqa(pc0, pD) + fqa(ps0, pG);
      float sv1 = fqa(pc1, pD) + fqa(ps1, pG);
      base[lane] = sv0; base[lane + 64] = sv1;
      m0 = fminf(m0, fminf(sv0, sv1)); M0 = fmaxf(M0, fmaxf(sv0, sv1));
    }
  }
  __shared__ float red[256];
  if (!do_write){
    float a = bred_min(m0, red), bb = bred_max(M0, red);
    float c = bred_min(m1, red), d = bred_max(M1, red);
    if (threadIdx.x == 0){
      atomicMin(&stats[slot_prod*16], f2o(a));     atomicMax(&stats[(slot_prod+1)*16], f2o(bb));
      atomicMin(&stats[(slot_prod+2)*16], f2o(c)); atomicMax(&stats[(slot_prod+3)*16], f2o(d));
    }
  } else {
    float a = bred_min(m0, red), bb = bred_max(M0, red);
    if (threadIdx.x == 0){ atomicMin(&stats[slot_sum*16], f2o(a)); atomicMax(&stats[(slot_sum+1)*16], f2o(bb)); }
  }
}

// V transpose + fq8(fq16) -> f16: vT[b][kv][d][t]
__global__ __launch_bounds__(256) void k_vT(const float* __restrict__ vlin, _Float16* __restrict__ vT,
                                            const unsigned* stats){
  FQP pv = fqp(dec_slot(stats, 6), dec_slot(stats, 7));
  float vlo = fqa(dec_slot(stats, 6), pv), vhi = fqa(dec_slot(stats, 7), pv);
  float v8s = fmaxf(fmaxf(fabsf(vlo), fabsf(vhi))/127.0f, 1e-12f), v8si = 1.0f/v8s;
  __shared__ float tile[64][65];
  int bkv = blockIdx.z, t0 = blockIdx.x << 6, d0 = blockIdx.y << 6;
  int b = bkv >> 3, kv = bkv & 7;
  const float* src = vlin + ((size_t)(b << 10))*1024 + (size_t)kv*128;
  int tx = threadIdx.x & 63, tq = threadIdx.x >> 6;
  #pragma unroll
  for (int i = 0; i < 16; i++){
    int tt = (i << 2) + tq;
    float x = src[(size_t)(t0 + tt)*1024 + d0 + tx];
    tile[tx][tt] = fq8(fqa(x, pv), v8s, v8si);
  }
  __syncthreads();
  _Float16* dst = vT + (size_t)bkv*131072;
  #pragma unroll
  for (int i = 0; i < 16; i++){
    int dd = (i << 2) + tq;
    dst[(size_t)(d0 + dd)*1024 + t0 + tx] = (_Float16)tile[dd][tx];
  }
}

extern "C" void kernel_launch(void* const* d_in, const int* in_sizes, int n_in,
                              void* d_out, int out_size, void* d_ws, size_t ws_size,
                              hipStream_t stream){
  (void)in_sizes; (void)n_in; (void)out_size; (void)ws_size;
  const float* hs   = (const float*)d_in[0];
  const float* cosp = (const float*)d_in[1];
  const float* sinp = (const float*)d_in[2];
  const float* Wq   = (const float*)d_in[4];
  const float* Wk   = (const float*)d_in[5];
  const float* Wv   = (const float*)d_in[6];
  const float* Wo   = (const float*)d_in[7];
  const float* qnw  = (const float*)d_in[8];
  const float* knw  = (const float*)d_in[9];

  float* outp = (float*)d_out;
  float* attn = outp + 4194304;      // final quantized softmax, written once by k_qk_pv

  const size_t MEG = 1u << 20;       // floats
  float* wsf = (float*)d_ws;
  _Float16* woq_h = (_Float16*)(wsf + 0);
  _Float16* wqq_h = (_Float16*)(wsf + 2*MEG);
  _Float16* wkq_h = (_Float16*)(wsf + 4*MEG);
  _Float16* wvq_h = (_Float16*)(wsf + 5*MEG);
  _Float16* hsq_h = (_Float16*)(wsf + 6*MEG);
  float* qlin = wsf + 8*MEG;  float* ctx = qlin;   // ctx reuses qlin (every elem stored by PV)
  float* klin = wsf + 12*MEG;
  float* vlin = wsf + 14*MEG;
  float* qbuf = wsf + 16*MEG;
  float* kbuf = wsf + 20*MEG;
  _Float16* q_h   = (_Float16*)(wsf + 22*MEG);
  _Float16* k_h   = (_Float16*)(wsf + 24*MEG);
  _Float16* vT_h  = (_Float16*)(wsf + 25*MEG);
  _Float16* ctx_h = (_Float16*)(wsf + 26*MEG);
  unsigned* rowmin = (unsigned*)(wsf + 28*MEG);
  unsigned* rowmax = (unsigned*)(wsf + 28*MEG + 32768);
  float* denomS = wsf + 28*MEG + 65536;
  unsigned* stats = (unsigned*)(wsf + 28*MEG + 98304);

  k_init<<<4, 256, 0, stream>>>(stats);

  k_quantw<<<4096, 256, 0, stream>>>(Wq, wqq_h);
  k_quantw<<<2048, 256, 0, stream>>>(Wk, wkq_h);
  k_quantw<<<2048, 256, 0, stream>>>(Wv, wvq_h);
  k_quantw<<<4096, 256, 0, stream>>>(Wo, woq_h);

  k_minmax<<<1024, 256, 0, stream>>>(hs, 4194304, stats, 0);
  k_fq_ew16<<<4096, 256, 0, stream>>>(hs, hsq_h, stats, 0);

  // projections (f16 MFMA, async LDS staging), raw-output range stats fused
  k_hgemm_f<<<dim3(16, 16), 256, 0, stream>>>(hsq_h, wqq_h, qlin, 2048, 2048, stats, 2);
  k_hgemm_kv<<<dim3(8, 16, 2), 256, 0, stream>>>(hsq_h, wkq_h, wvq_h, klin, vlin, 2048, stats);

  // fq16 + rmsnorm (fp32) + range reductions
  k_rms<<<1024, 256, 0, stream>>>(qlin, qbuf, qnw, stats, 2, 8, 16, 32768);
  k_rms<<<512, 256, 0, stream>>>(klin, kbuf, knw, stats, 4, 12, 8, 16384);

  // RoPE: range pass then write pass
  k_rope<<<1024, 256, 0, stream>>>(qbuf, cosp, sinp, stats, 8, 16, 24, 16, 32768, 0);
  k_rope<<<512, 256, 0, stream>>>(kbuf, cosp, sinp, stats, 12, 20, 26, 8, 16384, 0);
  k_rope<<<1024, 256, 0, stream>>>(qbuf, cosp, sinp, stats, 8, 16, 24, 16, 32768, 1);
  k_rope<<<512, 256, 0, stream>>>(kbuf, cosp, sinp, stats, 12, 20, 26, 8, 16384, 1);

  // operand conversion for QK and V transpose
  k_fq_ew16<<<4096, 256, 0, stream>>>(qbuf, q_h, stats, 24);
  k_fq8_ew16<<<2048, 256, 0, stream>>>(kbuf, k_h, stats, 26);
  k_vT<<<dim3(16, 2, 16), 256, 0, stream>>>(vlin, vT_h, stats);

  // 32-row-block attention passes (A-frags hoisted; no logit materialization)
  k_qk_stats<<<dim3(32, 32), 256, 0, stream>>>(q_h, k_h, stats, rowmin, rowmax);
  k_rowstat_m2<<<8, 256, 0, stream>>>(rowmin, stats, 32768);
  k_qk_denom<<<dim3(32, 32), 256, 0, stream>>>(q_h, k_h, rowmin, rowmax, denomS, stats);
  k_denom_min<<<8, 256, 0, stream>>>(denomS, stats, 32768);
  k_qk_pv<<<dim3(32, 32), 256, 0, stream>>>(q_h, k_h, vT_h, attn, ctx, rowmin, rowmax, denomS, stats);

  // ctx (stats fused in PV) -> f16 -> O-proj
  k_fq_ew16<<<4096, 256, 0, stream>>>(ctx, ctx_h, stats, 36);
  k_hgemm_f<<<dim3(16, 16), 256, 0, stream>>>(ctx_h, woq_h, outp, 2048, 2048, stats, -1);
}